// Round 13
// baseline (231.671 us; speedup 1.0000x reference)
//
#include <hip/hip_runtime.h>
#include <hip/hip_bf16.h>

typedef __attribute__((ext_vector_type(4))) int int4v;
typedef __attribute__((ext_vector_type(16))) int int16v;

#define TOKENS 8192
#define IN_F   4096
#define OUT_F  4096

// ws layout (bytes):
//   0     : double hdr[2]  (hdr[0]=mean, hdr[1]=scale)
//   1024  : double partials[1024]      (weight sums)
//   9216  : float  xpart[1024]         (per-block |x| max)
//   16384 : int8 q[TOKENS][IN_F]
//   16384 + TOKENS*IN_F: int8 s[OUT_F][IN_F]

__global__ __launch_bounds__(256) void k_pre(const float4* __restrict__ w,
                                             const float4* __restrict__ x,
                                             double* __restrict__ partials,
                                             float* __restrict__ xpart) {
  if (blockIdx.x < 1024) {
    __shared__ double sm[256];
    double s = 0.0;
    const float4* p = w + (size_t)blockIdx.x * 4096;
    for (int i = threadIdx.x; i < 4096; i += 256) {
      float4 v = p[i];
      s += (double)v.x + (double)v.y + (double)v.z + (double)v.w;
    }
    sm[threadIdx.x] = s;
    __syncthreads();
    for (int off = 128; off > 0; off >>= 1) {
      if (threadIdx.x < off) sm[threadIdx.x] += sm[threadIdx.x + off];
      __syncthreads();
    }
    if (threadIdx.x == 0) partials[blockIdx.x] = sm[0];
  } else {
    const int b = blockIdx.x - 1024;
    float m = 0.f;
    const size_t n = (size_t)TOKENS * IN_F / 4;
    for (size_t i = (size_t)b * 256 + threadIdx.x; i < n; i += (size_t)1024 * 256) {
      float4 v = x[i];
      m = fmaxf(m, fmaxf(fmaxf(fabsf(v.x), fabsf(v.y)),
                         fmaxf(fabsf(v.z), fabsf(v.w))));
    }
    __shared__ float smf[256];
    smf[threadIdx.x] = m;
    __syncthreads();
    for (int off = 128; off > 0; off >>= 1) {
      if (threadIdx.x < off) smf[threadIdx.x] = fmaxf(smf[threadIdx.x], smf[threadIdx.x + off]);
      __syncthreads();
    }
    if (threadIdx.x == 0) xpart[b] = smf[0];
  }
}

__global__ __launch_bounds__(256) void k_finalize(double* __restrict__ hdr,
                                                  const double* __restrict__ partials,
                                                  const float* __restrict__ xpart) {
  __shared__ double sm[256];
  __shared__ float smf[256];
  double s = partials[threadIdx.x] + partials[threadIdx.x + 256] +
             partials[threadIdx.x + 512] + partials[threadIdx.x + 768];
  float m = fmaxf(fmaxf(xpart[threadIdx.x], xpart[threadIdx.x + 256]),
                  fmaxf(xpart[threadIdx.x + 512], xpart[threadIdx.x + 768]));
  sm[threadIdx.x] = s;
  smf[threadIdx.x] = m;
  __syncthreads();
  for (int off = 128; off > 0; off >>= 1) {
    if (threadIdx.x < off) {
      sm[threadIdx.x] += sm[threadIdx.x + off];
      smf[threadIdx.x] = fmaxf(smf[threadIdx.x], smf[threadIdx.x + off]);
    }
    __syncthreads();
  }
  if (threadIdx.x == 0) {
    hdr[0] = sm[0] / (double)((size_t)OUT_F * IN_F);   // mean of weight
    hdr[1] = 127.0 / (double)smf[0];                   // absmax scale
  }
}

#define QB_BLK ((TOKENS * IN_F / 4) / 256)
#define TB_BLK ((OUT_F * IN_F / 4) / 256)
__global__ __launch_bounds__(256) void k_quant_tern(const float4* __restrict__ x,
                                                    const float4* __restrict__ w,
                                                    int* __restrict__ q,
                                                    int* __restrict__ sgn,
                                                    const double* __restrict__ hdr) {
  if (blockIdx.x < QB_BLK) {
    const double s = hdr[1];
    size_t i = (size_t)blockIdx.x * 256 + threadIdx.x;
    float4 v = x[i];
    int a = (int)rint(s * (double)v.x);
    int b = (int)rint(s * (double)v.y);
    int c = (int)rint(s * (double)v.z);
    int d = (int)rint(s * (double)v.w);
    q[i] = (a & 255) | ((b & 255) << 8) | ((c & 255) << 16) | ((d & 255) << 24);
  } else {
    const double m = hdr[0];
    size_t i = (size_t)(blockIdx.x - QB_BLK) * 256 + threadIdx.x;
    float4 v = w[i];
    int a = ((double)v.x > m) - ((double)v.x < m);
    int b = ((double)v.y > m) - ((double)v.y < m);
    int c = ((double)v.z > m) - ((double)v.z < m);
    int d = ((double)v.w > m) - ((double)v.w < m);
    sgn[i] = (a & 255) | ((b & 255) << 8) | ((c & 255) << 16) | ((d & 255) << 24);
  }
}

// ---------------------------------------------------------------------------
// int8 GEMM — exact R3 champion structure (256x256 tile, BK=64B, ring-4 LDS,
// 2 phases/K-tile, lgkm(0), vmcnt(8) never-drain, XOR swizzle, XCD map) with
// ONE change: 32x32x32 i8 MFMA instead of 16x16x64. Same FLOPs, same LDS
// bytes, HALF the MFMA instructions (16/wave/K-tile, each ~2x pipe-deep) —
// targets the issue-rate ceiling hypothesis.
// A/B frag (shape 32x32, K=32, 16B/lane): row = lane&31, k-half = lane>>5,
//   16B at k = (lane>>5)*16. LDS addr: row*64 + ((s ^ ((row>>1)&3))<<4),
//   s = ks*2 + (lane>>5). Conflict-free: per 8-row stripe the (parity,pos)
//   pairs spread 64 lanes 8-per-bank-quad = minimum sweep count.
// C/D (verified m74/m101, dtype-indep): col = lane&31,
//   row = (reg&3) + 8*(reg>>2) + 4*(lane>>5), reg in [0,16).
// ---------------------------------------------------------------------------
__device__ __forceinline__ void stage2(const signed char* __restrict__ gsrc,
                                       size_t grow0, int ktile,
                                       signed char* ldsbase, int tid, int wid) {
#pragma unroll
  for (int i = 0; i < 2; ++i) {
    const int slot = i * 512 + tid;     // per-lane source slot
    const int r = slot >> 2;            // row 0..255
    const int sir = slot & 3;           // stored 16B position in row
    const signed char* g = gsrc + (grow0 + (size_t)r) * IN_F +
                           (size_t)ktile * 64 + ((sir ^ ((r >> 1) & 3)) << 4);
    __builtin_amdgcn_global_load_lds(
        (const __attribute__((address_space(1))) void*)g,
        (__attribute__((address_space(3))) void*)(ldsbase + (i * 512 + wid * 64) * 16),
        16, 0, 0);
  }
}

__global__ __launch_bounds__(512, 2) void k_gemm(const signed char* __restrict__ q,
                                                 const signed char* __restrict__ s,
                                                 float* __restrict__ out) {
  __shared__ signed char sA[4][256 * 64];   // 64 KB
  __shared__ signed char sB[4][256 * 64];   // 64 KB
  const int tid  = threadIdx.x;
  const int lane = tid & 63;
  const int wid  = tid >> 6;     // 0..7
  const int wm   = wid >> 2;     // 0..1 -> row offset wm*128
  const int wn   = wid & 3;      // 0..3 -> col offset wn*64
  const int l31  = lane & 31;
  const int l5   = lane >> 5;

  // XCD-aware swizzle: 512 blocks, 8 XCDs, 64 blocks/XCD chunk (bijective)
  const int swz = (blockIdx.x & 7) * 64 + (blockIdx.x >> 3);
  const int bm = swz >> 4;       // 0..31
  const int bn = swz & 15;       // 0..15
  const size_t row0 = (size_t)bm * 256;
  const size_t col0 = (size_t)bn * 256;

  // per-lane read offsets (ks = K-half of the 64B tile row)
  const int x3 = (l31 >> 1) & 3;
  const int off_ks0 = l31 * 64 + (((0 + l5) ^ x3) << 4);   // s = ks*2+l5, ks=0
  const int off_ks1 = l31 * 64 + (((2 + l5) ^ x3) << 4);   // ks=1

  int16v acc[4][2];
#pragma unroll
  for (int i = 0; i < 4; ++i)
#pragma unroll
    for (int j = 0; j < 2; ++j)
#pragma unroll
      for (int r = 0; r < 16; ++r) acc[i][j][r] = 0;

  // prologue: stage tiles 0,1,2 into bufs 0,1,2
#pragma unroll
  for (int t = 0; t < 3; ++t) {
    stage2(q, row0, t, sA[t], tid, wid);
    stage2(s, col0, t, sB[t], tid, wid);
  }
  asm volatile("s_waitcnt vmcnt(8)" ::: "memory");   // tile 0 landed (own loads)
  __builtin_amdgcn_sched_barrier(0);
  __builtin_amdgcn_s_barrier();
  __builtin_amdgcn_sched_barrier(0);

  for (int kt = 0; kt < 64; ++kt) {
    const int c = kt & 3;
    const int pf   = (kt + 3) & 63;   // wrapped prefetch k-tile (uniform vmcnt)
    const int pbuf = (kt + 3) & 3;
    const signed char* bufA = sA[c];
    const signed char* bufB = sB[c];

    // ---- phase 0: read a[4][2] + b0[2]; stage A of kt+3; MFMA nf=0 ----
    int4v a[4][2], b0[2], b1[2];
#pragma unroll
    for (int mf = 0; mf < 4; ++mf) {
      const int base = (wm * 128 + mf * 32) * 64;
      a[mf][0] = *(const int4v*)(bufA + base + off_ks0);
      a[mf][1] = *(const int4v*)(bufA + base + off_ks1);
    }
    b0[0] = *(const int4v*)(bufB + (wn * 64) * 64 + off_ks0);
    b0[1] = *(const int4v*)(bufB + (wn * 64) * 64 + off_ks1);
    stage2(q, row0, pf, sA[pbuf], tid, wid);
    __builtin_amdgcn_sched_barrier(0);
    __builtin_amdgcn_s_barrier();
    asm volatile("s_waitcnt lgkmcnt(0)" ::: "memory");
    __builtin_amdgcn_sched_barrier(0);
    __builtin_amdgcn_s_setprio(1);
#pragma unroll
    for (int mf = 0; mf < 4; ++mf)
      acc[mf][0] = __builtin_amdgcn_mfma_i32_32x32x32_i8(a[mf][0], b0[0], acc[mf][0], 0, 0, 0);
#pragma unroll
    for (int mf = 0; mf < 4; ++mf)
      acc[mf][0] = __builtin_amdgcn_mfma_i32_32x32x32_i8(a[mf][1], b0[1], acc[mf][0], 0, 0, 0);
    __builtin_amdgcn_s_setprio(0);
    __builtin_amdgcn_sched_barrier(0);
    __builtin_amdgcn_s_barrier();

    // ---- phase 1: read b1[2]; stage B of kt+3; MFMA nf=1 ----
    b1[0] = *(const int4v*)(bufB + (wn * 64 + 32) * 64 + off_ks0);
    b1[1] = *(const int4v*)(bufB + (wn * 64 + 32) * 64 + off_ks1);
    stage2(s, col0, pf, sB[pbuf], tid, wid);
    __builtin_amdgcn_sched_barrier(0);
    __builtin_amdgcn_s_barrier();
    asm volatile("s_waitcnt lgkmcnt(0)" ::: "memory");
    __builtin_amdgcn_sched_barrier(0);
    __builtin_amdgcn_s_setprio(1);
#pragma unroll
    for (int mf = 0; mf < 4; ++mf)
      acc[mf][1] = __builtin_amdgcn_mfma_i32_32x32x32_i8(a[mf][0], b1[0], acc[mf][1], 0, 0, 0);
#pragma unroll
    for (int mf = 0; mf < 4; ++mf)
      acc[mf][1] = __builtin_amdgcn_mfma_i32_32x32x32_i8(a[mf][1], b1[1], acc[mf][1], 0, 0, 0);
    __builtin_amdgcn_s_setprio(0);
    // end of K-tile: ensure tile kt+1 landed everywhere before next iteration
    asm volatile("s_waitcnt vmcnt(8)" ::: "memory");
    __builtin_amdgcn_sched_barrier(0);
    __builtin_amdgcn_s_barrier();
    __builtin_amdgcn_sched_barrier(0);
  }

  // epilogue: 32x32 C/D mapping col = lane&31, row = (reg&3)+8*(reg>>2)+4*(lane>>5)
#pragma unroll
  for (int mf = 0; mf < 4; ++mf)
#pragma unroll
    for (int nf = 0; nf < 2; ++nf)
#pragma unroll
      for (int r = 0; r < 16; ++r) {
        const size_t rg = row0 + wm * 128 + mf * 32 + (r & 3) + 8 * (r >> 2) + 4 * l5;
        const size_t cg = col0 + wn * 64 + nf * 32 + l31;
        out[rg * OUT_F + cg] = (float)acc[mf][nf][r];
      }
}

extern "C" void kernel_launch(void* const* d_in, const int* in_sizes, int n_in,
                              void* d_out, int out_size, void* d_ws, size_t ws_size,
                              hipStream_t stream) {
  const float* x = (const float*)d_in[0];   // input  [8192][4096] f32
  const float* w = (const float*)d_in[1];   // weight [4096][4096] f32
  float* out = (float*)d_out;               // [8192][4096] f32

  char* ws = (char*)d_ws;
  double*   hdr      = (double*)ws;
  double*   partials = (double*)(ws + 1024);
  float*    xpart    = (float*)(ws + 9216);
  signed char* qbuf  = (signed char*)(ws + 16384);
  signed char* sbuf  = (signed char*)(ws + 16384 + (size_t)TOKENS * IN_F);

  k_pre<<<2048, 256, 0, stream>>>((const float4*)w, (const float4*)x, partials, xpart);
  k_finalize<<<1, 256, 0, stream>>>(hdr, partials, xpart);
  k_quant_tern<<<QB_BLK + TB_BLK, 256, 0, stream>>>((const float4*)x, (const float4*)w,
                                                    (int*)qbuf, (int*)sbuf, hdr);
  k_gemm<<<(TOKENS / 256) * (OUT_F / 256), 512, 0, stream>>>(qbuf, sbuf, out);
}

// Round 15
// 222.409 us; speedup vs baseline: 1.0416x; 1.0416x over previous
//
#include <hip/hip_runtime.h>
#include <hip/hip_bf16.h>

typedef __attribute__((ext_vector_type(4))) int int4v;

#define TOKENS 8192
#define IN_F   4096
#define OUT_F  4096

// ws layout (bytes):
//   0     : double hdr[2]  (hdr[0]=mean, hdr[1]=scale)
//   1024  : double partials[1024]
//   9216  : float  xpart[1024]
//   16384 : int8 q[TOKENS][IN_F]
//   16384 + TOKENS*IN_F: int8 s[OUT_F][IN_F]

__global__ __launch_bounds__(256) void k_pre(const float4* __restrict__ w,
                                             const float4* __restrict__ x,
                                             double* __restrict__ partials,
                                             float* __restrict__ xpart) {
  if (blockIdx.x < 1024) {
    __shared__ double sm[256];
    double s = 0.0;
    const float4* p = w + (size_t)blockIdx.x * 4096;
    for (int i = threadIdx.x; i < 4096; i += 256) {
      float4 v = p[i];
      s += (double)v.x + (double)v.y + (double)v.z + (double)v.w;
    }
    sm[threadIdx.x] = s;
    __syncthreads();
    for (int off = 128; off > 0; off >>= 1) {
      if (threadIdx.x < off) sm[threadIdx.x] += sm[threadIdx.x + off];
      __syncthreads();
    }
    if (threadIdx.x == 0) partials[blockIdx.x] = sm[0];
  } else {
    const int b = blockIdx.x - 1024;
    float m = 0.f;
    const size_t n = (size_t)TOKENS * IN_F / 4;
    for (size_t i = (size_t)b * 256 + threadIdx.x; i < n; i += (size_t)1024 * 256) {
      float4 v = x[i];
      m = fmaxf(m, fmaxf(fmaxf(fabsf(v.x), fabsf(v.y)),
                         fmaxf(fabsf(v.z), fabsf(v.w))));
    }
    __shared__ float smf[256];
    smf[threadIdx.x] = m;
    __syncthreads();
    for (int off = 128; off > 0; off >>= 1) {
      if (threadIdx.x < off) smf[threadIdx.x] = fmaxf(smf[threadIdx.x], smf[threadIdx.x + off]);
      __syncthreads();
    }
    if (threadIdx.x == 0) xpart[b] = smf[0];
  }
}

__global__ __launch_bounds__(256) void k_finalize(double* __restrict__ hdr,
                                                  const double* __restrict__ partials,
                                                  const float* __restrict__ xpart) {
  __shared__ double sm[256];
  __shared__ float smf[256];
  double s = partials[threadIdx.x] + partials[threadIdx.x + 256] +
             partials[threadIdx.x + 512] + partials[threadIdx.x + 768];
  float m = fmaxf(fmaxf(xpart[threadIdx.x], xpart[threadIdx.x + 256]),
                  fmaxf(xpart[threadIdx.x + 512], xpart[threadIdx.x + 768]));
  sm[threadIdx.x] = s;
  smf[threadIdx.x] = m;
  __syncthreads();
  for (int off = 128; off > 0; off >>= 1) {
    if (threadIdx.x < off) {
      sm[threadIdx.x] += sm[threadIdx.x + off];
      smf[threadIdx.x] = fmaxf(smf[threadIdx.x], smf[threadIdx.x + off]);
    }
    __syncthreads();
  }
  if (threadIdx.x == 0) {
    hdr[0] = sm[0] / (double)((size_t)OUT_F * IN_F);   // mean of weight
    hdr[1] = 127.0 / (double)smf[0];                   // absmax scale
  }
}

#define QB_BLK ((TOKENS * IN_F / 4) / 256)
#define TB_BLK ((OUT_F * IN_F / 4) / 256)
__global__ __launch_bounds__(256) void k_quant_tern(const float4* __restrict__ x,
                                                    const float4* __restrict__ w,
                                                    int* __restrict__ q,
                                                    int* __restrict__ sgn,
                                                    const double* __restrict__ hdr) {
  if (blockIdx.x < QB_BLK) {
    const double s = hdr[1];
    size_t i = (size_t)blockIdx.x * 256 + threadIdx.x;
    float4 v = x[i];
    int a = (int)rint(s * (double)v.x);
    int b = (int)rint(s * (double)v.y);
    int c = (int)rint(s * (double)v.z);
    int d = (int)rint(s * (double)v.w);
    q[i] = (a & 255) | ((b & 255) << 8) | ((c & 255) << 16) | ((d & 255) << 24);
  } else {
    const double m = hdr[0];
    size_t i = (size_t)(blockIdx.x - QB_BLK) * 256 + threadIdx.x;
    float4 v = w[i];
    int a = ((double)v.x > m) - ((double)v.x < m);
    int b = ((double)v.y > m) - ((double)v.y < m);
    int c = ((double)v.z > m) - ((double)v.z < m);
    int d = ((double)v.w > m) - ((double)v.w < m);
    sgn[i] = (a & 255) | ((b & 255) << 8) | ((c & 255) << 16) | ((d & 255) << 24);
  }
}

// ---------------------------------------------------------------------------
// int8 GEMM, 256x256 tile, BK=128B (32 K-tiles), ring-2 LDS (128 KB),
// 8 waves 2Mx4N, per-wave 128x64, 64 MFMA (16x16x64) per K-tile per wave.
// 4 phases/K-tile (m201 analog): each {ds_reads + stage; bar; lgkm(0);
// setprio; 16 MFMA; setprio; bar}. Stage of tile kt+1 spread P1 (4 A-units)
// + P2 (4 B-units); vmcnt(0) sits in P4 AFTER the MFMA cluster, when the 8
// gloads are 2-3 phases (~1500 cyc) old and L3-resident -> near-free.
// Swizzle (128B rows, 8 slots): stored pos p = s ^ (r&7) (involution; source
// pre-swizzled, gload dest linear - rule #21). Reads: quarter-wave hits each
// bank-quad with 2 lanes -> free (m136); whole wave 8 lanes/quad uniform.
// Safety: reads(kt) drained by P4's lgkm(0); P4-end barrier certifies all
// waves -> iter kt+1's stage may overwrite buf[kt&1]. Reads of tile kt+1
// (P1 of iter kt+1) follow the P4 vmcnt(0)+barrier that certified all units
// of tile kt+1 landed. All buffer indices static via 2x unroll (rule #20);
// sched_barrier(0) after every wait (rule #18).
// ---------------------------------------------------------------------------
__global__ __launch_bounds__(512, 2) void k_gemm(const signed char* __restrict__ q,
                                                 const signed char* __restrict__ s,
                                                 float* __restrict__ out) {
  __shared__ signed char sA[2][256 * 128];   // 64 KB
  __shared__ signed char sB[2][256 * 128];   // 64 KB
  const int tid  = threadIdx.x;
  const int lane = tid & 63;
  const int wid  = tid >> 6;     // 0..7
  const int wm   = wid >> 2;     // 0..1 -> row offset wm*128
  const int wn   = wid & 3;      // 0..3 -> col offset wn*64
  const int l15  = lane & 15, l4 = lane >> 4;

  // XCD-aware swizzle: 512 blocks, 8 XCDs, 64 blocks/XCD chunk (bijective)
  const int swz = (blockIdx.x & 7) * 64 + (blockIdx.x >> 3);
  const int bm = swz >> 4;       // 0..31
  const int bn = swz & 15;       // 0..15
  const size_t row0 = (size_t)bm * 256;
  const size_t col0 = (size_t)bn * 256;

  // read-offset precompute: logical 16B slot s in row r stored at s ^ (r&7)
  const int xr = l15 & 7;
  const int ksl0 = ((l4 ^ xr) << 4);        // ks=0 -> slot l4
  const int ksl1 = (((4 + l4) ^ xr) << 4);  // ks=1 -> slot 4+l4
  const int aRowBase = (wm * 128 + l15) * 128;
  const int bRowBase = (wn * 64 + l15) * 128;

#define SB0() __builtin_amdgcn_sched_barrier(0)

#define STAGE_T(GSRC, GROW0, KT, LDSBASE)                                       \
  do {                                                                          \
    const int kt_ = (KT);                                                       \
    _Pragma("unroll")                                                           \
    for (int u = 0; u < 4; ++u) {                                               \
      const int d = u * 512 + tid;                                              \
      const int r = d >> 3, p = d & 7;                                          \
      const int koff = ((p ^ (r & 7)) << 4);                                    \
      __builtin_amdgcn_global_load_lds(                                         \
          (const __attribute__((address_space(1))) void*)((GSRC) + ((GROW0) + (size_t)r) * IN_F + kt_ * 128 + koff), \
          (__attribute__((address_space(3))) void*)((LDSBASE) + (u * 512 + wid * 64) * 16), 16, 0, 0); \
    }                                                                           \
  } while (0)

#define RD_A8(BUF, AV, KSL)                                                     \
  do {                                                                          \
    _Pragma("unroll")                                                           \
    for (int f = 0; f < 8; ++f)                                                 \
      AV[f] = *(const int4v*)(sA[BUF] + aRowBase + f * 2048 + (KSL));           \
  } while (0)

#define RD_B2(BUF, BV, NB0, KSL)                                                \
  do {                                                                          \
    BV[0] = *(const int4v*)(sB[BUF] + bRowBase + (NB0) * 2048 + (KSL));         \
    BV[1] = *(const int4v*)(sB[BUF] + bRowBase + ((NB0) + 1) * 2048 + (KSL));   \
  } while (0)

#define MFMA16(AV, BV, NB)                                                      \
  do {                                                                          \
    _Pragma("unroll")                                                           \
    for (int m_ = 0; m_ < 8; ++m_) {                                            \
      acc[m_][NB]     = __builtin_amdgcn_mfma_i32_16x16x64_i8(AV[m_], BV[0],    \
                                                              acc[m_][NB], 0, 0, 0); \
      acc[m_][NB + 1] = __builtin_amdgcn_mfma_i32_16x16x64_i8(AV[m_], BV[1],    \
                                                              acc[m_][NB + 1], 0, 0, 0); \
    }                                                                           \
  } while (0)

#define PH_ENTER()                                                              \
  SB0();                                                                        \
  __builtin_amdgcn_s_barrier();                                                 \
  asm volatile("s_waitcnt lgkmcnt(0)" ::: "memory");                            \
  SB0();                                                                        \
  __builtin_amdgcn_s_setprio(1)

#define PH_EXIT()                                                               \
  __builtin_amdgcn_s_setprio(0);                                                \
  SB0();                                                                        \
  __builtin_amdgcn_s_barrier()

#define BODY(KT, CUR, NXT)                                                      \
  do {                                                                          \
    /* P1: a(k0) x8 + b01(k0); stage A(kt+1); MFMA n0,1 */                      \
    RD_A8(CUR, a0, ksl0);                                                       \
    RD_B2(CUR, bb, 0, ksl0);                                                    \
    STAGE_T(q, row0, ((KT) + 1) & 31, sA[NXT]);                                 \
    PH_ENTER();                                                                 \
    MFMA16(a0, bb, 0);                                                          \
    PH_EXIT();                                                                  \
    /* P2: b23(k0); stage B(kt+1); MFMA n2,3 */                                 \
    RD_B2(CUR, bb, 2, ksl0);                                                    \
    STAGE_T(s, col0, ((KT) + 1) & 31, sB[NXT]);                                 \
    PH_ENTER();                                                                 \
    MFMA16(a0, bb, 2);                                                          \
    PH_EXIT();                                                                  \
    /* P3: a(k1) x8 + b01(k1); MFMA n0,1 */                                     \
    RD_A8(CUR, a1, ksl1);                                                       \
    RD_B2(CUR, bb, 0, ksl1);                                                    \
    PH_ENTER();                                                                 \
    MFMA16(a1, bb, 0);                                                          \
    PH_EXIT();                                                                  \
    /* P4: b23(k1); MFMA n2,3; vmcnt(0) on 2-3-phase-old stages; barrier */     \
    RD_B2(CUR, bb, 2, ksl1);                                                    \
    SB0();                                                                      \
    __builtin_amdgcn_s_barrier();                                               \
    asm volatile("s_waitcnt lgkmcnt(0)" ::: "memory");                          \
    SB0();                                                                      \
    __builtin_amdgcn_s_setprio(1);                                              \
    MFMA16(a1, bb, 2);                                                          \
    __builtin_amdgcn_s_setprio(0);                                              \
    SB0();                                                                      \
    asm volatile("s_waitcnt vmcnt(0)" ::: "memory");                            \
    SB0();                                                                      \
    __builtin_amdgcn_s_barrier();                                               \
    SB0();                                                                      \
  } while (0)

  int4v acc[8][4];
#pragma unroll
  for (int i = 0; i < 8; ++i)
#pragma unroll
    for (int j = 0; j < 4; ++j) acc[i][j] = int4v{0, 0, 0, 0};

  int4v a0[8], a1[8], bb[2];

  // prologue: stage tile 0 into buf 0 (8 gloads); drain; barrier.
  STAGE_T(q, row0, 0, sA[0]);
  STAGE_T(s, col0, 0, sB[0]);
  SB0();
  asm volatile("s_waitcnt vmcnt(0)" ::: "memory");
  SB0();
  __builtin_amdgcn_s_barrier();
  SB0();

  for (int kt = 0; kt < 32; kt += 2) {
    BODY(kt + 0, 0, 1);
    BODY(kt + 1, 1, 0);
  }

  // epilogue: C/D mapping col = lane&15, row = (lane>>4)*4 + r
#pragma unroll
  for (int m = 0; m < 8; ++m)
#pragma unroll
    for (int n = 0; n < 4; ++n)
#pragma unroll
      for (int r = 0; r < 4; ++r) {
        const size_t rg = row0 + wm * 128 + m * 16 + l4 * 4 + r;
        const size_t cg = col0 + wn * 64 + n * 16 + l15;
        out[rg * OUT_F + cg] = (float)acc[m][n][r];
      }

#undef SB0
#undef STAGE_T
#undef RD_A8
#undef RD_B2
#undef MFMA16
#undef PH_ENTER
#undef PH_EXIT
#undef BODY
}

extern "C" void kernel_launch(void* const* d_in, const int* in_sizes, int n_in,
                              void* d_out, int out_size, void* d_ws, size_t ws_size,
                              hipStream_t stream) {
  const float* x = (const float*)d_in[0];   // input  [8192][4096] f32
  const float* w = (const float*)d_in[1];   // weight [4096][4096] f32
  float* out = (float*)d_out;               // [8192][4096] f32

  char* ws = (char*)d_ws;
  double*   hdr      = (double*)ws;
  double*   partials = (double*)(ws + 1024);
  float*    xpart    = (float*)(ws + 9216);
  signed char* qbuf  = (signed char*)(ws + 16384);
  signed char* sbuf  = (signed char*)(ws + 16384 + (size_t)TOKENS * IN_F);

  k_pre<<<2048, 256, 0, stream>>>((const float4*)w, (const float4*)x, partials, xpart);
  k_finalize<<<1, 256, 0, stream>>>(hdr, partials, xpart);
  k_quant_tern<<<QB_BLK + TB_BLK, 256, 0, stream>>>((const float4*)x, (const float4*)w,
                                                    (int*)qbuf, (int*)sbuf, hdr);
  k_gemm<<<(TOKENS / 256) * (OUT_F / 256), 512, 0, stream>>>(qbuf, sbuf, out);
}